// Round 3
// baseline (239.360 us; speedup 1.0000x reference)
//
#include <hip/hip_runtime.h>

#define Bsz 256
#define Dd  4096
#define MAXR 15
#define FMAX 3.402823466e+38f

typedef short bf16x8 __attribute__((ext_vector_type(8)));
typedef float f32x4  __attribute__((ext_vector_type(4)));

__device__ __forceinline__ unsigned short f2bf(float f) {
    unsigned int u = __float_as_uint(f);
    unsigned int r = (u + 0x7fffu + ((u >> 16) & 1u)) >> 16;   // RNE
    return (unsigned short)r;
}
__device__ __forceinline__ float bf2f(unsigned short h) {
    return __uint_as_float(((unsigned int)h) << 16);
}

// ---------------- Kernel 1: x (fp32 binary) -> bf16 (exact) ----------------
__global__ void k_xcvt(const float* __restrict__ x, unsigned short* __restrict__ xb) {
    int i = blockIdx.x * blockDim.x + threadIdx.x;
    xb[i] = f2bf(x[i]);
}

// ------- Kernel 2: S = 0.5*(W + W^T), split into bf16 hi + lo planes -------
__global__ void k_ssym(const float* __restrict__ W,
                       unsigned short* __restrict__ shi,
                       unsigned short* __restrict__ slo) {
    __shared__ float wt[64][65];                 // +1 pad: conflict-free transpose read
    int tx = threadIdx.x & 63;
    int ty = threadIdx.x >> 6;                   // 0..3
    int i0 = blockIdx.y * 64, j0 = blockIdx.x * 64;
    #pragma unroll
    for (int rr = 0; rr < 16; ++rr) {
        int j = ty + rr * 4;
        wt[j][tx] = W[(size_t)(j0 + j) * Dd + i0 + tx];   // wt[j][i] = W[j0+j][i0+i]
    }
    __syncthreads();
    #pragma unroll
    for (int rr = 0; rr < 16; ++rr) {
        int i = ty + rr * 4;
        float s = 0.5f * (W[(size_t)(i0 + i) * Dd + j0 + tx] + wt[tx][i]);
        unsigned short hi = f2bf(s);
        unsigned short lo = f2bf(s - bf2f(hi));
        size_t o = (size_t)(i0 + i) * Dd + j0 + tx;
        shi[o] = hi;
        slo[o] = lo;
    }
}

// --------- Kernel 3: grad = X @ S + bias  (MFMA bf16 hi/lo split) ----------
// grid (N/64, M/64) = (64, 4); 512 threads = 8 waves (4 along M x 2 along N)
__global__ __launch_bounds__(512) void k_gemm(const unsigned short* __restrict__ xb,
                                              const unsigned short* __restrict__ shi,
                                              const unsigned short* __restrict__ slo,
                                              const float* __restrict__ bias,
                                              float* __restrict__ gout) {
    __shared__ __align__(16) unsigned short As[64][72];   // [m][k], +8 pad
    __shared__ __align__(16) unsigned short Bh[64][72];   // [n][k] == S[n0+n][k] (symmetric)
    __shared__ __align__(16) unsigned short Bl[64][72];
    const int tid  = threadIdx.x;
    const int m0   = blockIdx.y * 64, n0 = blockIdx.x * 64;
    const int w    = tid >> 6, lane = tid & 63;
    const int wm   = w & 3, wn = w >> 2;          // wave tile: rows wm*16, cols wn*32
    const int ln   = lane & 15, quad = lane >> 4;
    const int srow = tid >> 3, sc0 = (tid & 7) * 8;

    f32x4 acc[2];
    #pragma unroll
    for (int c = 0; c < 2; ++c)
        #pragma unroll
        for (int r = 0; r < 4; ++r) acc[c][r] = 0.0f;

    const size_t arow = (size_t)(m0 + srow) * Dd + sc0;
    const size_t brow = (size_t)(n0 + srow) * Dd + sc0;

    for (int k0 = 0; k0 < Dd; k0 += 64) {
        __syncthreads();
        *(uint4*)&As[srow][sc0] = *(const uint4*)(xb  + arow + k0);
        *(uint4*)&Bh[srow][sc0] = *(const uint4*)(shi + brow + k0);
        *(uint4*)&Bl[srow][sc0] = *(const uint4*)(slo + brow + k0);
        __syncthreads();
        #pragma unroll
        for (int kk = 0; kk < 64; kk += 32) {
            bf16x8 a = *(const bf16x8*)&As[wm * 16 + ln][kk + quad * 8];
            #pragma unroll
            for (int c = 0; c < 2; ++c) {
                bf16x8 bh = *(const bf16x8*)&Bh[wn * 32 + c * 16 + ln][kk + quad * 8];
                bf16x8 bl = *(const bf16x8*)&Bl[wn * 32 + c * 16 + ln][kk + quad * 8];
                acc[c] = __builtin_amdgcn_mfma_f32_16x16x32_bf16(a, bh, acc[c], 0, 0, 0);
                acc[c] = __builtin_amdgcn_mfma_f32_16x16x32_bf16(a, bl, acc[c], 0, 0, 0);
            }
        }
    }
    // C/D layout (m89-verified): col = lane&15, row = quad*4 + reg
    #pragma unroll
    for (int c = 0; c < 2; ++c)
        #pragma unroll
        for (int r = 0; r < 4; ++r) {
            int m = wm * 16 + quad * 4 + r;
            int n = wn * 32 + c * 16 + ln;
            gout[(size_t)(m0 + m) * Dd + n0 + n] = acc[c][r] + bias[n0 + n];
        }
}

// ---------------- block reduction helpers (256 threads = 4 waves) ----------------
__device__ __forceinline__ float block_max256(float v, float* redf) {
    #pragma unroll
    for (int off = 32; off; off >>= 1) v = fmaxf(v, __shfl_down(v, off));
    __syncthreads();
    if ((threadIdx.x & 63) == 0) redf[threadIdx.x >> 6] = v;
    __syncthreads();
    return fmaxf(fmaxf(redf[0], redf[1]), fmaxf(redf[2], redf[3]));
}
__device__ __forceinline__ float block_sum256(float v, float* redf) {
    #pragma unroll
    for (int off = 32; off; off >>= 1) v += __shfl_down(v, off);
    __syncthreads();
    if ((threadIdx.x & 63) == 0) redf[threadIdx.x >> 6] = v;
    __syncthreads();
    return (redf[0] + redf[1]) + (redf[2] + redf[3]);    // fixed order: deterministic
}
__device__ __forceinline__ void block_argmax256(float v, int idx, float* redf, int* redi,
                                                float& bv, int& bi) {
    #pragma unroll
    for (int off = 32; off; off >>= 1) {
        float v2 = __shfl_down(v, off);
        int   i2 = __shfl_down(idx, off);
        if (v2 > v || (v2 == v && i2 < idx)) { v = v2; idx = i2; }
    }
    __syncthreads();
    if ((threadIdx.x & 63) == 0) { redf[threadIdx.x >> 6] = v; redi[threadIdx.x >> 6] = idx; }
    __syncthreads();
    bv = redf[0]; bi = redi[0];
    #pragma unroll
    for (int w2 = 1; w2 < 4; ++w2) {
        float v2 = redf[w2]; int i2 = redi[w2];
        if (v2 > bv || (v2 == bv && i2 < bi)) { bv = v2; bi = i2; }
    }
}

// ---------------- Kernel 4: per-row epilogue (block = one sample) ----------------
// `out` enters holding grad (written by k_gemm), exits holding the final sample.
__global__ __launch_bounds__(256) void k_epilogue(const float* __restrict__ x,
                                                  const float* __restrict__ W,
                                                  const int* __restrict__ radius_raw,
                                                  const float* __restrict__ gu,
                                                  const float* __restrict__ uvec,
                                                  float* __restrict__ out) {
    __shared__ float scx_s[Dd];
    __shared__ float key_s[Dd];
    __shared__ float redf[4];
    __shared__ int   redi[4];
    __shared__ int   flips[MAXR];

    const int b = blockIdx.x;
    const int tid = threadIdx.x;
    const float* grow  = out + (size_t)b * Dd;
    const float* xrow  = x   + (size_t)b * Dd;
    const float* gurow = gu  + (size_t)b * Dd;

    // phase 1: score_change_x and gumbel keys
    float lmax = -FMAX;
    for (int j = tid; j < Dd; j += 256) {
        float g  = grow[j];
        float xv = xrow[j];
        float sc = (1.0f - 2.0f * xv) * g * 0.5f;
        float uu = fmaxf(gurow[j], 1e-10f);           // upper clip is a no-op in fp32
        float gn = -logf(-logf(uu));
        scx_s[j] = sc;
        key_s[j] = sc + gn;
        lmax = fmaxf(lmax, sc);
    }
    // lse_x
    float mx = block_max256(lmax, redf);
    float ls = 0.0f;
    for (int j = tid; j < Dd; j += 256) ls += expf(scx_s[j] - mx);
    float lse_x = mx + logf(block_sum256(ls, redf));

    // top-radius via sequential block argmax (tie -> lowest index, matches lax.top_k)
    const int radius = radius_raw[b] + 1;             // in [1, 15]
    for (int t = 0; t < radius; ++t) {
        float v = -FMAX; int idx = 0x7fffffff;
        for (int j = tid; j < Dd; j += 256) {
            float kv = key_s[j];
            if (kv > v) { v = kv; idx = j; }
        }
        float bv; int bi;
        block_argmax256(v, idx, redf, redi, bv, bi);
        if (tid == 0) { flips[t] = bi; key_s[bi] = -FMAX; }
        __syncthreads();
    }

    // lse_y: scx with sign flipped at flip positions
    float lmy = -FMAX;
    for (int j = tid; j < Dd; j += 256) {
        float v = scx_s[j];
        for (int t = 0; t < radius; ++t) if (j == flips[t]) v = -v;
        lmy = fmaxf(lmy, v);
    }
    float my = block_max256(lmy, redf);
    float lsy = 0.0f;
    for (int j = tid; j < Dd; j += 256) {
        float v = scx_s[j];
        for (int t = 0; t < radius; ++t) if (j == flips[t]) v = -v;
        lsy += expf(v - my);
    }
    float lse_y = my + logf(block_sum256(lsy, redf));

    // pair term: log_pypx + log_tilde_pxpy = 0.25 * sum_{p,q} d_p d_q (W_pq + W_qp)
    float ts = 0.0f;
    for (int t = tid; t < radius * radius; t += 256) {
        int p = flips[t / radius], q = flips[t % radius];
        float dp = 1.0f - 2.0f * xrow[p];
        float dq = 1.0f - 2.0f * xrow[q];
        ts += 0.25f * dp * dq * (W[(size_t)p * Dd + q] + W[(size_t)q * Dd + p]);
    }
    float T = block_sum256(ts, redf);

    float log_acc = fminf(T + lse_x - lse_y, 0.0f);
    int accepted = (expf(log_acc) > uvec[b]) ? 1 : 0;

    // write output: x everywhere, flips overwritten iff accepted
    __syncthreads();
    float* orow = out + (size_t)b * Dd;
    for (int j = tid; j < Dd; j += 256) orow[j] = xrow[j];
    __syncthreads();
    if (accepted && tid < radius) {
        int p = flips[tid];
        orow[p] = 1.0f - xrow[p];
    }
}

extern "C" void kernel_launch(void* const* d_in, const int* in_sizes, int n_in,
                              void* d_out, int out_size, void* d_ws, size_t ws_size,
                              hipStream_t stream) {
    const float* x          = (const float*)d_in[0];
    const float* W          = (const float*)d_in[1];
    const float* bias       = (const float*)d_in[2];
    const int*   radius_raw = (const int*)d_in[3];
    const float* gu         = (const float*)d_in[4];
    const float* u          = (const float*)d_in[5];
    float* out = (float*)d_out;

    // workspace: S_hi (33.55 MB) | S_lo (33.55 MB) | X_bf16 (2 MB)  = 69,206,016 B
    unsigned short* shi = (unsigned short*)d_ws;
    unsigned short* slo = shi + (size_t)Dd * Dd;
    unsigned short* xb  = slo + (size_t)Dd * Dd;

    k_xcvt<<<(Bsz * Dd) / 256, 256, 0, stream>>>(x, xb);
    k_ssym<<<dim3(64, 64), 256, 0, stream>>>(W, shi, slo);
    k_gemm<<<dim3(64, 4), 512, 0, stream>>>(xb, shi, slo, bias, out);
    k_epilogue<<<Bsz, 256, 0, stream>>>(x, W, radius_raw, gu, u, out);
}